// Round 1
// baseline (276.561 us; speedup 1.0000x reference)
//
#include <hip/hip_runtime.h>

// DNM_Linear_M3: out[b,o] = k * (sum_m sigmoid( sum_i W2[i]*sigmoid(0.5*(x[b,i]*W[o,m,i]-q[o,m,i])) ) - qs)
// B=64, OUT=512, M=5, IN=1024.  ~167.8M inner sigmoids -> transcendental-bound.
//
// Mapping: block = one o (grid 512), 320 threads = 5 waves, wave -> m, lane -> b.
// The length-1024 i-reduction is per-lane serial (no cross-lane ops in hot loop).
// x staged per-chunk into LDS transposed so lane-b access is conflict-free LDS
// instead of a 4KB-stride global gather.

constexpr int B_    = 64;
constexpr int OUT_  = 512;
constexpr int M_    = 5;
constexpr int IN_   = 1024;
constexpr int CHUNK = 128;          // i's per LDS chunk
constexpr int PITCH = 65;           // pad: stores stride 65 dwords -> conflict-free

__global__ __launch_bounds__(320)
void dnm_kernel(const float* __restrict__ x,
                const float* __restrict__ W,
                const float* __restrict__ Q,
                const float* __restrict__ W2,
                const float* __restrict__ kk,
                const float* __restrict__ qs,
                float* __restrict__ out)
{
    __shared__ float xs[CHUNK * PITCH];   // 33,280 B
    __shared__ float sigred[M_ * 64];     //  1,280 B

    const int o   = blockIdx.x;
    const int tid = threadIdx.x;
    // wave-uniform m (readfirstlane so W/Q row addresses are SGPR -> s_load)
    const int m   = __builtin_amdgcn_readfirstlane(tid >> 6);
    const int b   = tid & 63;

    // sigmoid(0.5*(xw - q)) = 1 / (1 + 2^( C*(xw - q) )),  C = -0.5*log2(e)
    const float C = -0.72134752044448170368f;

    const float* Wrow = W + (o * M_ + m) * IN_;
    const float* Qrow = Q + (o * M_ + m) * IN_;

    float acc = 0.0f;

    for (int i0 = 0; i0 < IN_; i0 += CHUNK) {
        __syncthreads();   // previous chunk fully consumed before overwrite
        // stage x[:, i0:i0+CHUNK] -> xs[ii*PITCH + b] (transposed)
        for (int idx = tid; idx < B_ * CHUNK; idx += 320) {
            const int bb = idx >> 7;          // CHUNK == 128
            const int ii = idx & (CHUNK - 1);
            xs[ii * PITCH + bb] = x[bb * IN_ + i0 + ii];
        }
        __syncthreads();

        #pragma unroll 8
        for (int ii = 0; ii < CHUNK; ++ii) {
            const float w   = Wrow[i0 + ii];      // s_load (uniform)
            const float cw  = C * w;              // folded scale (uniform VALU)
            const float ncq = -C * Qrow[i0 + ii]; // s_load + uniform VALU
            const float xv  = xs[ii * PITCH + b]; // ds_read_b32, 2-way (free)
            const float t   = fmaf(xv, cw, ncq);
            const float e   = __builtin_amdgcn_exp2f(t);        // v_exp_f32
            const float r   = __builtin_amdgcn_rcpf(1.0f + e);  // v_rcp_f32
            acc = fmaf(W2[i0 + ii], r, acc);      // W2 uniform -> 1 sgpr operand
        }
    }

    // outer sigmoid over the dendritic sum (d ~ 250 -> saturates to 1.0f)
    const float e2 = __builtin_amdgcn_exp2f(-1.4426950408889634f * acc);
    const float sd = __builtin_amdgcn_rcpf(1.0f + e2);

    sigred[m * 64 + b] = sd;
    __syncthreads();
    if (tid < 64) {
        const float y = sigred[b] + sigred[64 + b] + sigred[128 + b]
                      + sigred[192 + b] + sigred[256 + b];
        out[b * OUT_ + o] = kk[0] * (y - qs[0]);
    }
}

extern "C" void kernel_launch(void* const* d_in, const int* in_sizes, int n_in,
                              void* d_out, int out_size, void* d_ws, size_t ws_size,
                              hipStream_t stream) {
    const float* x   = (const float*)d_in[0];
    const float* W   = (const float*)d_in[1];   // Synapse_W  (OUT, M, IN)
    const float* Q   = (const float*)d_in[2];   // Synapse_q  (OUT, M, IN)
    const float* W2  = (const float*)d_in[3];   // Dendritic_W2 (IN,)
    const float* kk  = (const float*)d_in[4];   // k  (1,)
    const float* qs  = (const float*)d_in[5];   // qs (1,)
    float* out = (float*)d_out;                 // (B, OUT) fp32

    dnm_kernel<<<OUT_, 320, 0, stream>>>(x, W, Q, W2, kk, qs, out);
}

// Round 2
// 157.165 us; speedup vs baseline: 1.7597x; 1.7597x over previous
//
#include <hip/hip_runtime.h>

// DNM_Linear_M3: out[b,o] = k * (sum_m sigmoid( sum_i W2[i]*sigmoid(0.5*(x[b,i]*W[o,m,i]-q[o,m,i])) ) - qs)
// B=64, OUT=512, M=5, IN=1024.
//
// Round 2 mapping: block = o (grid 512), 320 threads = 5 waves, wave = m.
// lane = i-quad: lane owns i = c*256 + 4*lane + {0..3}. W/Q/W2 loaded as
// coalesced dwordx4 ONCE per chunk (vector path, not the slow scalar pipe)
// and reused across the serial b=0..63 inner loop. x read per-b as coalesced
// float4 (L1/L2 resident). Per-lane acc[64] registers; butterfly transpose-
// reduce puts d[b] on lane b. No LDS / barriers in the hot loop.

constexpr int B_   = 64;
constexpr int OUT_ = 512;
constexpr int M_   = 5;
constexpr int IN_  = 1024;

// sigmoid(0.5*(xw - q)) = 1 / (1 + 2^( C*(xw - q) )),  C = -0.5*log2(e)
constexpr float C_   = -0.72134752044448170368f;
constexpr float L2E_ =  1.4426950408889634f;

__global__ __launch_bounds__(320, 3)
void dnm_kernel(const float* __restrict__ x,
                const float* __restrict__ W,
                const float* __restrict__ Q,
                const float* __restrict__ W2,
                const float* __restrict__ kk,
                const float* __restrict__ qs,
                float* __restrict__ out)
{
    __shared__ float sigred[M_ * 64];

    const int o    = blockIdx.x;
    const int tid  = threadIdx.x;
    const int m    = __builtin_amdgcn_readfirstlane(tid >> 6);
    const int lane = tid & 63;

    const float* Wrow = W + (o * M_ + m) * IN_;
    const float* Qrow = Q + (o * M_ + m) * IN_;

    float acc[64];
    #pragma unroll
    for (int b = 0; b < 64; ++b) acc[b] = 0.0f;

    // outer chunk loop NOT unrolled (keep code size ~1 body = I$-friendly)
    for (int c = 0; c < IN_ / 256; ++c) {
        const int i0 = c * 256 + 4 * lane;

        const float4 w4 = *(const float4*)(Wrow + i0);   // coalesced dwordx4
        const float4 q4 = *(const float4*)(Qrow + i0);
        const float4 v2 = *(const float4*)(W2   + i0);

        const float cw0 = C_ * w4.x, cw1 = C_ * w4.y, cw2 = C_ * w4.z, cw3 = C_ * w4.w;
        const float nq0 = -C_ * q4.x, nq1 = -C_ * q4.y, nq2 = -C_ * q4.z, nq3 = -C_ * q4.w;

        const float* xp = x + i0;

        #pragma unroll   // full unroll: acc[] must stay in registers
        for (int b = 0; b < 64; ++b) {
            const float4 xv = *(const float4*)(xp + b * IN_);  // coalesced, L1/L2-hit
            const float t0 = fmaf(xv.x, cw0, nq0);
            const float t1 = fmaf(xv.y, cw1, nq1);
            const float t2 = fmaf(xv.z, cw2, nq2);
            const float t3 = fmaf(xv.w, cw3, nq3);
            const float r0 = __builtin_amdgcn_rcpf(1.0f + __builtin_amdgcn_exp2f(t0));
            const float r1 = __builtin_amdgcn_rcpf(1.0f + __builtin_amdgcn_exp2f(t1));
            const float r2 = __builtin_amdgcn_rcpf(1.0f + __builtin_amdgcn_exp2f(t2));
            const float r3 = __builtin_amdgcn_rcpf(1.0f + __builtin_amdgcn_exp2f(t3));
            const float s  = fmaf(v2.x, r0, fmaf(v2.y, r1, fmaf(v2.z, r2, v2.w * r3)));
            acc[b] += s;
        }
    }

    // Butterfly transpose-reduce: 64 per-lane partials -> lane b holds
    // d[b] = sum over all lanes (i.e. over all i) of acc[b].
    #pragma unroll
    for (int off = 32; off >= 1; off >>= 1) {
        const bool up = (lane & off) != 0;
        #pragma unroll
        for (int j = 0; j < off; ++j) {
            const float keep = up ? acc[j + off] : acc[j];
            const float send = up ? acc[j]       : acc[j + off];
            acc[j] = keep + __shfl_xor(send, off, 64);
        }
    }

    // lane == b now.  Outer sigmoid (d ~ 250 -> saturates, numerics trivial).
    const float d  = acc[0];
    const float sd = __builtin_amdgcn_rcpf(1.0f + __builtin_amdgcn_exp2f(-L2E_ * d));

    sigred[tid] = sd;                 // tid == m*64 + lane
    __syncthreads();
    if (tid < 64) {
        const float y = sigred[tid] + sigred[64 + tid] + sigred[128 + tid]
                      + sigred[192 + tid] + sigred[256 + tid];
        out[tid * OUT_ + o] = kk[0] * (y - qs[0]);
    }
}

extern "C" void kernel_launch(void* const* d_in, const int* in_sizes, int n_in,
                              void* d_out, int out_size, void* d_ws, size_t ws_size,
                              hipStream_t stream) {
    const float* x   = (const float*)d_in[0];
    const float* W   = (const float*)d_in[1];   // Synapse_W  (OUT, M, IN)
    const float* Q   = (const float*)d_in[2];   // Synapse_q  (OUT, M, IN)
    const float* W2  = (const float*)d_in[3];   // Dendritic_W2 (IN,)
    const float* kk  = (const float*)d_in[4];   // k  (1,)
    const float* qs  = (const float*)d_in[5];   // qs (1,)
    float* out = (float*)d_out;                 // (B, OUT) fp32

    dnm_kernel<<<OUT_, 320, 0, stream>>>(x, W, Q, W2, kk, qs, out);
}

// Round 3
// 134.345 us; speedup vs baseline: 2.0586x; 1.1699x over previous
//
#include <hip/hip_runtime.h>

// DNM_Linear_M3: out[b,o] = k * (sum_m sigmoid( sum_i W2[i]*sigmoid(0.5*(x[b,i]*W[o,m,i]-q[o,m,i])) ) - qs)
// B=64, OUT=512, M=5, IN=1024.
//
// Round 3: round 2's acc[64] spilled to scratch (VGPR=52 < 64, WRITE_SIZE
// 1024KB vs 128KB out = spill leakage). Split batch across blocks:
// grid = (OUT, 4 b-groups), wave = m, lane = i-quad, acc[16] only -> stays
// in registers. 10240 waves total (10/SIMD) for latency hiding.

constexpr int OUT_ = 512;
constexpr int M_   = 5;
constexpr int IN_  = 1024;
constexpr int TB_  = 16;        // b's per block
constexpr int BG_  = 4;         // b-groups (TB_*BG_ == B == 64)

// sigmoid(0.5*(xw - q)) = 1 / (1 + 2^( C*(xw - q) )),  C = -0.5*log2(e)
constexpr float C_   = -0.72134752044448170368f;
constexpr float L2E_ =  1.4426950408889634f;

__global__ __launch_bounds__(320, 6)   // cap ~84 VGPR: acc[16]+consts+pipelined x loads, no spill
void dnm_kernel(const float* __restrict__ x,
                const float* __restrict__ W,
                const float* __restrict__ Q,
                const float* __restrict__ W2,
                const float* __restrict__ kk,
                const float* __restrict__ qs,
                float* __restrict__ out)
{
    __shared__ float sigred[M_ * TB_];

    const int o    = blockIdx.x;
    const int b0   = blockIdx.y * TB_;
    const int tid  = threadIdx.x;
    const int m    = __builtin_amdgcn_readfirstlane(tid >> 6);
    const int lane = tid & 63;

    const float* Wrow = W + (o * M_ + m) * IN_;
    const float* Qrow = Q + (o * M_ + m) * IN_;

    float acc[TB_];
    #pragma unroll
    for (int b = 0; b < TB_; ++b) acc[b] = 0.0f;

    for (int c = 0; c < IN_ / 256; ++c) {
        const int i0 = c * 256 + 4 * lane;

        const float4 w4 = *(const float4*)(Wrow + i0);   // coalesced dwordx4
        const float4 q4 = *(const float4*)(Qrow + i0);
        const float4 v2 = *(const float4*)(W2   + i0);

        const float cw0 = C_ * w4.x, cw1 = C_ * w4.y, cw2 = C_ * w4.z, cw3 = C_ * w4.w;
        const float nq0 = -C_ * q4.x, nq1 = -C_ * q4.y, nq2 = -C_ * q4.z, nq3 = -C_ * q4.w;

        const float* xp = x + b0 * IN_ + i0;

        #pragma unroll   // TB_=16 static indices: acc[] stays in VGPRs
        for (int b = 0; b < TB_; ++b) {
            const float4 xv = *(const float4*)(xp + b * IN_);  // coalesced, L1/L2-hit
            const float t0 = fmaf(xv.x, cw0, nq0);
            const float t1 = fmaf(xv.y, cw1, nq1);
            const float t2 = fmaf(xv.z, cw2, nq2);
            const float t3 = fmaf(xv.w, cw3, nq3);
            const float r0 = __builtin_amdgcn_rcpf(1.0f + __builtin_amdgcn_exp2f(t0));
            const float r1 = __builtin_amdgcn_rcpf(1.0f + __builtin_amdgcn_exp2f(t1));
            const float r2 = __builtin_amdgcn_rcpf(1.0f + __builtin_amdgcn_exp2f(t2));
            const float r3 = __builtin_amdgcn_rcpf(1.0f + __builtin_amdgcn_exp2f(t3));
            acc[b] += fmaf(v2.x, r0, fmaf(v2.y, r1, fmaf(v2.z, r2, v2.w * r3)));
        }
    }

    // Fold lanes so all four 16-lane groups hold identical partials...
    #pragma unroll
    for (int j = 0; j < TB_; ++j) {
        acc[j] += __shfl_xor(acc[j], 16, 64);
        acc[j] += __shfl_xor(acc[j], 32, 64);
    }
    // ...then butterfly transpose-reduce within 16-lane groups:
    // lane (l&15) ends holding d for b = b0 + (l&15).
    #pragma unroll
    for (int off = 8; off >= 1; off >>= 1) {
        const bool up = (lane & off) != 0;
        #pragma unroll
        for (int j = 0; j < off; ++j) {
            const float keep = up ? acc[j + off] : acc[j];
            const float send = up ? acc[j]       : acc[j + off];
            acc[j] = keep + __shfl_xor(send, off, 64);
        }
    }

    // Outer sigmoid (d ~ 250 -> saturates; numerics trivial).
    const float d  = acc[0];
    const float sd = __builtin_amdgcn_rcpf(1.0f + __builtin_amdgcn_exp2f(-L2E_ * d));

    if (lane < TB_) sigred[m * TB_ + lane] = sd;
    __syncthreads();
    if (tid < TB_) {
        const float y = sigred[tid] + sigred[TB_ + tid] + sigred[2 * TB_ + tid]
                      + sigred[3 * TB_ + tid] + sigred[4 * TB_ + tid];
        out[(b0 + tid) * OUT_ + o] = kk[0] * (y - qs[0]);
    }
}

extern "C" void kernel_launch(void* const* d_in, const int* in_sizes, int n_in,
                              void* d_out, int out_size, void* d_ws, size_t ws_size,
                              hipStream_t stream) {
    const float* x   = (const float*)d_in[0];
    const float* W   = (const float*)d_in[1];   // Synapse_W  (OUT, M, IN)
    const float* Q   = (const float*)d_in[2];   // Synapse_q  (OUT, M, IN)
    const float* W2  = (const float*)d_in[3];   // Dendritic_W2 (IN,)
    const float* kk  = (const float*)d_in[4];   // k  (1,)
    const float* qs  = (const float*)d_in[5];   // qs (1,)
    float* out = (float*)d_out;                 // (B, OUT) fp32

    dnm_kernel<<<dim3(OUT_, BG_), 320, 0, stream>>>(x, W, Q, W2, kk, qs, out);
}